// Round 3
// baseline (153.733 us; speedup 1.0000x reference)
//
#include <hip/hip_runtime.h>

#define GD    256   // G*D latent row stride
#define DIM   64
#define KCB   1024
#define KT    256   // codewords per tile (per block)
#define NROW  32768 // rows per group (B*T)
#define NTOT  131072 // 4 groups * NROW

typedef float floatx4 __attribute__((ext_vector_type(4)));
typedef __bf16 bf16x8 __attribute__((ext_vector_type(8)));
typedef unsigned int uint;

union ABu { bf16x8 v; __bf16 h[8]; uint4 u4; };

// ---------------------------------------------------------------------------
// Kernel A: per-tile scoring + argmin via packed-key global atomicMin.
// grid 2048 = 4 groups x 128 row-chunks x 4 K-tiles; 256 thr, 33 KB LDS,
// 4 blocks/CU -> up to 32 waves/CU for latency hiding.
// ---------------------------------------------------------------------------
extern "C" __global__ void __launch_bounds__(256, 4)
vq_score(const float* __restrict__ latents, const float* __restrict__ cbg,
         uint* __restrict__ keys, float* __restrict__ xsq_g)
{
    __shared__ __attribute__((aligned(16))) uint cb_lds[KT * 32]; // 32 KB, XOR swizzled
    __shared__ float initv_lds[KT];

    const int tid  = threadIdx.x;
    const int wave = tid >> 6;
    const int lane = tid & 63;
    const int l15  = lane & 15;
    const int quad = lane >> 4;

    const int bid   = blockIdx.x;
    const int tile  = bid & 3;
    const int chunk = (bid >> 2) & 127;
    const int g     = bid >> 9;
    const int wRow0 = chunk * 256 + wave * 64;   // token row within group

    const float* __restrict__ cbgrp = cbg + (size_t)g * (KCB * DIM);

    // ---- stage this block's 256-codeword tile fp32->bf16; initv = -csq/2-0.5 ----
    {
        const int kk = tid;
        const float* src = cbgrp + (size_t)(tile * KT + kk) * DIM;
        float csq = 0.f;
        #pragma unroll
        for (int c = 0; c < 8; ++c) {
            float4 f0 = *(const float4*)(src + c * 8);
            float4 f1 = *(const float4*)(src + c * 8 + 4);
            csq += f0.x*f0.x + f0.y*f0.y + f0.z*f0.z + f0.w*f0.w
                 + f1.x*f1.x + f1.y*f1.y + f1.z*f1.z + f1.w*f1.w;
            ABu t;
            t.h[0] = (__bf16)f0.x; t.h[1] = (__bf16)f0.y;
            t.h[2] = (__bf16)f0.z; t.h[3] = (__bf16)f0.w;
            t.h[4] = (__bf16)f1.x; t.h[5] = (__bf16)f1.y;
            t.h[6] = (__bf16)f1.z; t.h[7] = (__bf16)f1.w;
            const int dc = c ^ (kk & 7);
            *(uint4*)&cb_lds[kk * 32 + dc * 4] = t.u4;
        }
        initv_lds[kk] = -0.5f * csq - 0.5f;   // makes every score < 0
    }

    // ---- load A fragments (64 rows/wave) + per-row x_sq ----
    bf16x8 afrag[4][2];
    #pragma unroll
    for (int rt = 0; rt < 4; ++rt) {
        const int row = wRow0 + rt * 16 + l15;
        const float* src = latents + (size_t)row * GD + g * DIM + quad * 8;
        float xp = 0.f;
        #pragma unroll
        for (int ks = 0; ks < 2; ++ks) {
            float4 f0 = *(const float4*)(src + ks * 32);
            float4 f1 = *(const float4*)(src + ks * 32 + 4);
            xp += f0.x*f0.x + f0.y*f0.y + f0.z*f0.z + f0.w*f0.w
                + f1.x*f1.x + f1.y*f1.y + f1.z*f1.z + f1.w*f1.w;
            ABu a;
            a.h[0] = (__bf16)f0.x; a.h[1] = (__bf16)f0.y;
            a.h[2] = (__bf16)f0.z; a.h[3] = (__bf16)f0.w;
            a.h[4] = (__bf16)f1.x; a.h[5] = (__bf16)f1.y;
            a.h[6] = (__bf16)f1.z; a.h[7] = (__bf16)f1.w;
            afrag[rt][ks] = a.v;
        }
        xp += __shfl_xor(xp, 16);
        xp += __shfl_xor(xp, 32);
        if (tile == 0 && quad == 0)
            xsq_g[g * NROW + wRow0 + rt * 16 + l15] = xp;
    }
    __syncthreads();

    // preload per-lane init values for all 16 t-iterations (breaks per-iter dep)
    float vinit[16];
    #pragma unroll
    for (int t = 0; t < 16; ++t) vinit[t] = initv_lds[t * 16 + l15];

    uint best[4][4];
    #pragma unroll
    for (int rt = 0; rt < 4; ++rt)
        #pragma unroll
        for (int r = 0; r < 4; ++r) best[rt][r] = 0xFFFFFFFFu;

    #pragma unroll 4
    for (int t = 0; t < 16; ++t) {
        const int kkl = t * 16 + l15;       // tile-local codeword this lane scores
        const float v = vinit[t];
        ABu b0, b1;
        b0.u4 = *(const uint4*)&cb_lds[kkl * 32 + (((quad    ) ^ (kkl & 7)) << 2)];
        b1.u4 = *(const uint4*)&cb_lds[kkl * 32 + (((quad + 4) ^ (kkl & 7)) << 2)];
        const uint kcol = (uint)(tile * KT + kkl);
        #pragma unroll
        for (int rt = 0; rt < 4; ++rt) {
            floatx4 acc = { v, v, v, v };
            acc = __builtin_amdgcn_mfma_f32_16x16x32_bf16(afrag[rt][0], b0.v, acc, 0, 0, 0);
            acc = __builtin_amdgcn_mfma_f32_16x16x32_bf16(afrag[rt][1], b1.v, acc, 0, 0, 0);
            // score < 0 always -> raw fp32 bits monotone decreasing.
            // Pack codeword idx in low 10 bits; min_u32 = argmin.
            #pragma unroll
            for (int r = 0; r < 4; ++r) {
                const uint key = (__float_as_uint(acc[r]) & 0xFFFFFC00u) | kcol;
                best[rt][r] = best[rt][r] < key ? best[rt][r] : key;
            }
        }
    }

    // ---- reduce over the 16 column lanes, then cross-block combine ----
    #pragma unroll
    for (int rt = 0; rt < 4; ++rt) {
        #pragma unroll
        for (int r = 0; r < 4; ++r) {
            uint kmin = best[rt][r];
            #pragma unroll
            for (int m = 1; m <= 8; m <<= 1) {
                const uint o = (uint)__shfl_xor((int)kmin, m);
                kmin = o < kmin ? o : kmin;
            }
            if (l15 == 0)
                atomicMin(&keys[g * NROW + wRow0 + rt * 16 + quad * 4 + r], kmin);
        }
    }
}

// ---------------------------------------------------------------------------
// Kernel B: read keys, gather fp32 codewords, stream output, loss.
// ---------------------------------------------------------------------------
extern "C" __global__ void __launch_bounds__(256, 4)
vq_emit(const uint* __restrict__ keys, const float* __restrict__ xsq_g,
        const float* __restrict__ cbg, float* __restrict__ out,
        float* __restrict__ loss)
{
    __shared__ float part[4];
    const int tid  = threadIdx.x;
    const int wave = tid >> 6;
    const int lane = tid & 63;
    const int l15  = lane & 15;
    const int quad = lane >> 4;

    const int wbase = (blockIdx.x * 4 + wave) * 16;   // first (g,row) index of wave
    float lsum = 0.f;
    #pragma unroll
    for (int i = 0; i < 4; ++i) {
        const int rg = wbase + i * 4 + quad;          // global row idx in [0, NTOT)
        const int g  = rg >> 15;
        const int n  = rg & (NROW - 1);
        const uint key = keys[rg];
        const int kidx = (int)(key & 1023u);
        const float4 cw =
            ((const float4*)(cbg + (size_t)g * (KCB * DIM)))[(size_t)kidx * 16 + l15];
        ((float4*)out)[(size_t)n * 64 + g * 16 + l15] = cw;
        if (l15 == 0) {
            // dist = x_sq - 2*score - 1  (score = x.c - csq/2 - 0.5)
            const float sc = __uint_as_float(key & 0xFFFFFC00u);
            lsum += xsq_g[rg] - 2.f * sc - 1.f;
        }
    }
    #pragma unroll
    for (int m = 1; m <= 32; m <<= 1) lsum += __shfl_xor(lsum, m);
    if (lane == 0) part[wave] = lsum;
    __syncthreads();
    if (tid == 0)
        atomicAdd(loss, (part[0] + part[1] + part[2] + part[3]) * (1.25f / 8388608.0f));
}

extern "C" void kernel_launch(void* const* d_in, const int* in_sizes, int n_in,
                              void* d_out, int out_size, void* d_ws, size_t ws_size,
                              hipStream_t stream)
{
    const float* latents = (const float*)d_in[0];
    const float* cbg     = (const float*)d_in[1];
    float* out   = (float*)d_out;
    float* lossp = out + 8388608;            // quantized [8*4096*256] then scalar loss

    uint*  keys  = (uint*)d_ws;              // NTOT u32 = 512 KB
    float* xsq_g = (float*)d_ws + NTOT;      // NTOT f32 = 512 KB

    hipMemsetAsync(keys, 0xFF, NTOT * sizeof(uint), stream);  // all-ones > any real key
    hipMemsetAsync(lossp, 0, sizeof(float), stream);
    vq_score<<<dim3(2048), dim3(256), 0, stream>>>(latents, cbg, keys, xsq_g);
    vq_emit <<<dim3(2048), dim3(256), 0, stream>>>(keys, xsq_g, cbg, out, lossp);
}

// Round 4
// 137.146 us; speedup vs baseline: 1.1209x; 1.1209x over previous
//
#include <hip/hip_runtime.h>

#define GD    256   // G*D latent row stride
#define DIM   64
#define KCB   1024
#define KT    256   // codewords per tile (per block)
#define NROW  32768 // rows per group (B*T)
#define NTOT  131072

typedef float floatx4 __attribute__((ext_vector_type(4)));
typedef __bf16 bf16x8 __attribute__((ext_vector_type(8)));
typedef unsigned int uint;

union ABu { bf16x8 v; __bf16 h[8]; uint4 u4; };

// ---------------------------------------------------------------------------
// Kernel A: tile scoring + argmin via packed-key global atomicMin.
// grid 2048 = (g, row-chunk, tile fastest); 256 thr, 33 KB LDS, 4 blocks/CU.
// Staging is lane-contiguous (16 lines/wave-instr, the coalescing minimum).
// ---------------------------------------------------------------------------
extern "C" __global__ void __launch_bounds__(256, 4)
vq_score(const float* __restrict__ latents, const float* __restrict__ cbg,
         uint* __restrict__ keys, float* __restrict__ xsq_g)
{
    __shared__ __attribute__((aligned(16))) uint cb_lds[KT * 32]; // 32 KB, XOR swizzled
    __shared__ float initv_lds[KT];

    const int tid  = threadIdx.x;
    const int wave = tid >> 6;
    const int lane = tid & 63;
    const int l15  = lane & 15;
    const int quad = lane >> 4;

    const int bid   = blockIdx.x;
    const int tile  = bid & 3;          // fastest: 4 tile-blocks share rows (L2/L3 reuse)
    const int chunk = (bid >> 2) & 127;
    const int g     = bid >> 9;
    const int wRow0 = chunk * 256 + wave * 64;

    const float* __restrict__ cbgrp = cbg + (size_t)g * (KCB * DIM);

    // ---- stage 256-codeword tile, fully coalesced ----
    // tile is contiguous 64 KB: thread tid takes float4 #(i*256+tid);
    // row r = idx>>4, 8B-chunk c8 = tid&15. csq by 16-lane butterfly.
    {
        const float4* __restrict__ src4 =
            (const float4*)(cbgrp + (size_t)(tile * KT) * DIM);
        #pragma unroll
        for (int i = 0; i < 16; ++i) {
            const int idx = i * 256 + tid;
            const float4 f = src4[idx];
            const int r  = idx >> 4;
            const int c8 = tid & 15;
            float d = f.x*f.x + f.y*f.y + f.z*f.z + f.w*f.w;
            d += __shfl_xor(d, 1);
            d += __shfl_xor(d, 2);
            d += __shfl_xor(d, 4);
            d += __shfl_xor(d, 8);
            union { __bf16 h[4]; uint2 u2; } t;
            t.h[0] = (__bf16)f.x; t.h[1] = (__bf16)f.y;
            t.h[2] = (__bf16)f.z; t.h[3] = (__bf16)f.w;
            const int w = r * 32 + (((c8 >> 1) ^ (r & 7)) << 2) + ((c8 & 1) << 1);
            *(uint2*)&cb_lds[w] = t.u2;
            if (c8 == 0) initv_lds[r] = -0.5f * d - 0.5f;  // every score < 0
        }
    }

    // ---- load A fragments (64 rows/wave) + per-row x_sq ----
    bf16x8 afrag[4][2];
    #pragma unroll
    for (int rt = 0; rt < 4; ++rt) {
        const int row = wRow0 + rt * 16 + l15;
        const float* src = latents + (size_t)row * GD + g * DIM + quad * 8;
        float xp = 0.f;
        #pragma unroll
        for (int ks = 0; ks < 2; ++ks) {
            float4 f0 = *(const float4*)(src + ks * 32);
            float4 f1 = *(const float4*)(src + ks * 32 + 4);
            xp += f0.x*f0.x + f0.y*f0.y + f0.z*f0.z + f0.w*f0.w
                + f1.x*f1.x + f1.y*f1.y + f1.z*f1.z + f1.w*f1.w;
            ABu a;
            a.h[0] = (__bf16)f0.x; a.h[1] = (__bf16)f0.y;
            a.h[2] = (__bf16)f0.z; a.h[3] = (__bf16)f0.w;
            a.h[4] = (__bf16)f1.x; a.h[5] = (__bf16)f1.y;
            a.h[6] = (__bf16)f1.z; a.h[7] = (__bf16)f1.w;
            afrag[rt][ks] = a.v;
        }
        xp += __shfl_xor(xp, 16);
        xp += __shfl_xor(xp, 32);
        if (tile == 0 && quad == 0)
            xsq_g[g * NROW + wRow0 + rt * 16 + l15] = xp;
    }
    __syncthreads();

    // preload per-lane init values for all 16 t-iterations
    float vinit[16];
    #pragma unroll
    for (int t = 0; t < 16; ++t) vinit[t] = initv_lds[t * 16 + l15];

    uint best[4][4];
    #pragma unroll
    for (int rt = 0; rt < 4; ++rt)
        #pragma unroll
        for (int r = 0; r < 4; ++r) best[rt][r] = 0xFFFFFFFFu;

    #pragma unroll 4
    for (int t = 0; t < 16; ++t) {
        const int kkl = t * 16 + l15;
        const float v = vinit[t];
        ABu b0, b1;
        b0.u4 = *(const uint4*)&cb_lds[kkl * 32 + (((quad    ) ^ (kkl & 7)) << 2)];
        b1.u4 = *(const uint4*)&cb_lds[kkl * 32 + (((quad + 4) ^ (kkl & 7)) << 2)];
        const uint kcol = (uint)(tile * KT + kkl);
        #pragma unroll
        for (int rt = 0; rt < 4; ++rt) {
            floatx4 acc = { v, v, v, v };
            acc = __builtin_amdgcn_mfma_f32_16x16x32_bf16(afrag[rt][0], b0.v, acc, 0, 0, 0);
            acc = __builtin_amdgcn_mfma_f32_16x16x32_bf16(afrag[rt][1], b1.v, acc, 0, 0, 0);
            // score < 0 -> fp32 bits monotone decreasing; pack idx, min_u32.
            #pragma unroll
            for (int r = 0; r < 4; ++r) {
                const uint key = (__float_as_uint(acc[r]) & 0xFFFFFC00u) | kcol;
                best[rt][r] = best[rt][r] < key ? best[rt][r] : key;
            }
        }
    }

    // ---- reduce over the 16 column lanes, then cross-block combine ----
    #pragma unroll
    for (int rt = 0; rt < 4; ++rt) {
        #pragma unroll
        for (int r = 0; r < 4; ++r) {
            uint kmin = best[rt][r];
            #pragma unroll
            for (int m = 1; m <= 8; m <<= 1) {
                const uint o = (uint)__shfl_xor((int)kmin, m);
                kmin = o < kmin ? o : kmin;
            }
            if (l15 == 0)
                atomicMin(&keys[g * NROW + wRow0 + rt * 16 + quad * 4 + r], kmin);
        }
    }
}

// ---------------------------------------------------------------------------
// Kernel B: wave = 16 rows x all 4 groups (quad = group). Dense 1 KB row
// writes (16 lines/instr, optimal); key broadcast via shfl; loss fused.
// grid 512 x 256 thr, no LDS tiles.
// ---------------------------------------------------------------------------
extern "C" __global__ void __launch_bounds__(256, 4)
vq_emit(const uint* __restrict__ keys, const float* __restrict__ xsq_g,
        const float* __restrict__ cbg, float* __restrict__ out,
        float* __restrict__ loss)
{
    __shared__ float part[4];
    const int tid  = threadIdx.x;
    const int wave = tid >> 6;
    const int lane = tid & 63;
    const int l15  = lane & 15;
    const int quad = lane >> 4;          // group index (G == 4)
    const int n0   = blockIdx.x * 64 + wave * 16;

    // this lane owns (g=quad, row=n0+l15) for key/xsq/loss purposes
    const uint  key_l = keys [quad * NROW + n0 + l15];
    const float xsq_l = xsq_g[quad * NROW + n0 + l15];
    const float sc_l  = __uint_as_float(key_l & 0xFFFFFC00u);
    float lsum = xsq_l - 2.f * sc_l - 1.f;   // dist = x_sq - 2*score - 1

    const float4* __restrict__ cb4 = (const float4*)cbg;
    float4* __restrict__ out4 = (float4*)out;
    const int gbase = quad * (KCB * DIM / 4);   // quad doubles as output group
    #pragma unroll
    for (int j = 0; j < 16; ++j) {
        const uint key = (uint)__shfl((int)key_l, (lane & 48) + j);
        const int kidx = (int)(key & 1023u);
        const float4 cw = cb4[gbase + kidx * 16 + l15];
        out4[(size_t)(n0 + j) * 64 + lane] = cw;   // dense 1 KB per wave-instr
    }

    #pragma unroll
    for (int m = 1; m <= 32; m <<= 1) lsum += __shfl_xor(lsum, m);
    if (lane == 0) part[wave] = lsum;
    __syncthreads();
    if (tid == 0)
        atomicAdd(loss, (part[0] + part[1] + part[2] + part[3]) * (1.25f / 8388608.0f));
}

extern "C" void kernel_launch(void* const* d_in, const int* in_sizes, int n_in,
                              void* d_out, int out_size, void* d_ws, size_t ws_size,
                              hipStream_t stream)
{
    const float* latents = (const float*)d_in[0];
    const float* cbg     = (const float*)d_in[1];
    float* out   = (float*)d_out;
    float* lossp = out + 8388608;            // quantized [8*4096*256] then scalar loss

    uint*  keys  = (uint*)d_ws;              // NTOT u32
    float* xsq_g = (float*)d_ws + NTOT;      // NTOT f32

    hipMemsetAsync(keys, 0xFF, NTOT * sizeof(uint), stream);
    hipMemsetAsync(lossp, 0, sizeof(float), stream);
    vq_score<<<dim3(2048), dim3(256), 0, stream>>>(latents, cbg, keys, xsq_g);
    vq_emit <<<dim3(512),  dim3(256), 0, stream>>>(keys, xsq_g, cbg, out, lossp);
}